// Round 18
// baseline (13.404 us; speedup 1.0000x reference)
//
#include <hip/hip_runtime.h>
#include <math.h>

// FBPINN: out(x) = sum_k w_k(x)*subnet_k(x) / sum_k w_k(x), x scalar in [0,1].
// Two dispatches:
//  1) build_tables, POINT-PER-QUAD: block = (32-pt stretch, slot); 128 thr
//     (2 waves). Lane = (point p, row-group m): computes 8 of 32 rows per
//     layer; cross-lane exchange via DPP quad_perm (VALU, zero DS-pipe use).
//     Weights in LDS transposed, stride 36 (b128-aligned, m-groups hit banks
//     {0,8,16,24}, conflict-free broadcast). Build is DS-pipe-throughput
//     bound (confirmed R15/R16/R17: DPP removal and two T-halvings all moved
//     time as modeled) -> T=2048 with 32-pt stretches halves per-CU DS work
//     again: 2 waves x ~134 b128 x 12cyc ~ 3.2K cyc ~ 1.4us.
//     Slot coverage: 3.72 + 16*31/2047 = 3.96 < 4 -> 4 slots cover.
//  2) eval_lerp: two float4 loads fetch 8 interleaved table entries; sum of
//     4 lerps = lerp of sum; denominator ANALYTIC (<=4 cosine windows).
// Lerp error ~1.2e-4 at TBL=2048 << 7.3e-3 threshold (bf16 floor 1.95e-3).

#define KSUB 16
#define NW 32
#define TBL 2048
#define PSTR 32               // points per stretch
#define NSTR (TBL / PSTR)     // 64 stretches
#define SLOTS 4
#define BTHR 128              // 2 waves
#define STR36 36              // padded transposed row stride (floats)
// LDS offsets (floats)
#define OW1T 0                // [32][36] transposed W1
#define OW2T 1152             // [32][36] transposed W2
#define OT0  2304             // W0[32] B0[32] B1[32] B2[32] W3[32]
#define LDSF 2464

// tanh(x) = 1 - 2/(exp(2x)+1); v_exp_f32 is exp2 -> scale by 2*log2(e).
static __device__ __forceinline__ float fast_tanh(float v) {
    float e = __builtin_amdgcn_exp2f(v * 2.8853900817779268f);
    return 1.0f - 2.0f * __builtin_amdgcn_rcpf(e + 1.0f);
}

static __device__ __forceinline__ float cos_pi(float u) {
    return __builtin_amdgcn_cosf(0.5f * u);   // v_cos takes revolutions
}

static __device__ __forceinline__ float window_w(float x, int k) {
    const float invTW = 20.0f;  // 1/0.05
    float xmin = (float)k * 0.0625f - 0.06f;
    float xmax = (float)(k + 1) * 0.0625f + 0.06f;
    float up = (x - xmin + 0.025f) * invTW;
    float dn = (xmax + 0.025f - x) * invTW;
    up = fminf(fmaxf(up, 0.0f), 1.0f);
    dn = fminf(fmaxf(dn, 0.0f), 1.0f);
    return 0.25f * (1.0f - cos_pi(up)) * (1.0f - cos_pi(dn));
}

// Active subnets at x: k in (16x-2.36, 16x+1.36) => at most 4, klo..klo+3.
static __device__ __forceinline__ float den_analytic(float xv) {
    int klo = (int)ceilf(16.0f * xv - 2.36f);
    float den = 0.f;
#pragma unroll
    for (int j = 0; j < 4; ++j) {
        int k = klo + j;
        if (k >= 0 && k < KSUB) den += window_w(xv, k);
    }
    return den;
}

// DPP quad_perm lane exchange within each aligned quad (VALU, no DS pipe).
// ctrl = p0|p1<<2|p2<<4|p3<<6 : xor1=0xB1, xor2=0x4E, xor3=0x1B.
template <int CTRL>
static __device__ __forceinline__ float dpp_quad(float v) {
    return __uint_as_float(__builtin_amdgcn_mov_dpp(
        __float_as_uint(v), CTRL, 0xF, 0xF, true));
}
static __device__ __forceinline__ float quad_xor(float v, int e) {
    // e is a compile-time constant under full unroll
    if (e == 1) return dpp_quad<0xB1>(v);
    if (e == 2) return dpp_quad<0x4E>(v);
    if (e == 3) return dpp_quad<0x1B>(v);
    return v;
}

// One hidden layer, quad-split: lane owns rows [m*8, m*8+8).
#define QLAYER(WTOFS, BOFS, hin, hout)                                      \
    {                                                                       \
        float acc[8];                                                       \
        {                                                                   \
            float4 bA = *reinterpret_cast<const float4*>(&R[(BOFS) + m8]);  \
            float4 bB = *reinterpret_cast<const float4*>(&R[(BOFS) + m8 + 4]); \
            acc[0] = bA.x; acc[1] = bA.y; acc[2] = bA.z; acc[3] = bA.w;     \
            acc[4] = bB.x; acc[5] = bB.y; acc[6] = bB.z; acc[7] = bB.w;     \
        }                                                                   \
        _Pragma("unroll")                                                   \
        for (int e = 0; e < 4; ++e) {                                       \
            const int src8 = ((m ^ e) << 3);                                \
            _Pragma("unroll")                                               \
            for (int j2 = 0; j2 < 8; ++j2) {                                \
                float v = quad_xor(hin[j2], e);                             \
                float4 wA = *reinterpret_cast<const float4*>(               \
                    &R[(WTOFS) + (src8 + j2) * STR36 + m8]);                \
                float4 wB = *reinterpret_cast<const float4*>(               \
                    &R[(WTOFS) + (src8 + j2) * STR36 + m8 + 4]);            \
                acc[0] = fmaf(wA.x, v, acc[0]);                             \
                acc[1] = fmaf(wA.y, v, acc[1]);                             \
                acc[2] = fmaf(wA.z, v, acc[2]);                             \
                acc[3] = fmaf(wA.w, v, acc[3]);                             \
                acc[4] = fmaf(wB.x, v, acc[4]);                             \
                acc[5] = fmaf(wB.y, v, acc[5]);                             \
                acc[6] = fmaf(wB.z, v, acc[6]);                             \
                acc[7] = fmaf(wB.w, v, acc[7]);                             \
            }                                                               \
        }                                                                   \
        _Pragma("unroll")                                                   \
        for (int j = 0; j < 8; ++j) hout[j] = fast_tanh(acc[j]);            \
    }

// grid = NSTR*SLOTS = 256 blocks x 128 threads (2 waves, 16 pts/wave).
__global__ __launch_bounds__(BTHR) void build_tables(
    const float* __restrict__ W0, const float* __restrict__ B0,
    const float* __restrict__ W1, const float* __restrict__ B1,
    const float* __restrict__ W2, const float* __restrict__ B2,
    const float* __restrict__ W3, const float* __restrict__ B3,
    float* __restrict__ g)
{
    __shared__ float R[LDSF];   // 9.6 KB

    const int t    = threadIdx.x;         // 0..127
    const int str  = blockIdx.x >> 2;
    const int slot = blockIdx.x & 3;
    const float inv = 1.0f / (float)(TBL - 1);

    float x_lo = (float)(str * PSTR) * inv;
    int klo_b = (int)ceilf(16.0f * x_lo - 2.36f);
    const int k  = klo_b + slot;          // block-uniform
    const int kc = min(max(k, 0), KSUB - 1);

    // ---- stage weights: W1/W2 transposed (stride 36), tail linear ----
    {
        const float4* gW1 = reinterpret_cast<const float4*>(&W1[kc * NW * NW]);
        const float4* gW2 = reinterpret_cast<const float4*>(&W2[kc * NW * NW]);
#pragma unroll
        for (int c = 0; c < 2; ++c) {
            const int tt = t + c * BTHR;  // 0..255
            float4 v1 = gW1[tt];
            float4 v2 = gW2[tt];
            int r  = (4 * tt) >> 5;       // source row (output index)
            int c2 = (4 * tt) & 31;       // source col (input index)
            R[OW1T + (c2 + 0) * STR36 + r] = v1.x;
            R[OW1T + (c2 + 1) * STR36 + r] = v1.y;
            R[OW1T + (c2 + 2) * STR36 + r] = v1.z;
            R[OW1T + (c2 + 3) * STR36 + r] = v1.w;
            R[OW2T + (c2 + 0) * STR36 + r] = v2.x;
            R[OW2T + (c2 + 1) * STR36 + r] = v2.y;
            R[OW2T + (c2 + 2) * STR36 + r] = v2.z;
            R[OW2T + (c2 + 3) * STR36 + r] = v2.w;
        }
        {
            const int a = t >> 5, e = t & 31;   // a in 0..3
            const float* sp = (a == 0) ? &W0[kc * NW] :
                              (a == 1) ? &B0[kc * NW] :
                              (a == 2) ? &B1[kc * NW] : &B2[kc * NW];
            R[OT0 + t] = sp[e];
        }
        if (t < 32) R[OT0 + 128 + t] = W3[kc * NW + t];
    }
    __syncthreads();

    // ---- lane roles ----
    const int m  = t & 3;                 // row-group
    const int m8 = m << 3;
    const int p  = (t >> 2) & 15;         // point within wave
    const int wv = t >> 6;                // wave id (0..1)
    const int pi = str * PSTR + wv * 16 + p;
    const float xg = (float)pi * inv;

    const float INVS = 10.958904109589041f;  // 1/0.09125 (uniform scale)
    const float ctr  = ((float)kc + 0.5f) * 0.0625f;
    const float xn = (xg - ctr) * INVS;

    // layer 0: lane's 8 rows
    float h[8], h2[8];
#pragma unroll
    for (int j = 0; j < 8; ++j) {
        float w0 = R[OT0 + m8 + j];
        float b0 = R[OT0 + 32 + m8 + j];
        h[j] = fast_tanh(fmaf(w0, xn, b0));
    }
    // layers 1 & 2 (quad-split, DPP exchange)
    QLAYER(OW1T, OT0 + 64, h, h2);
    QLAYER(OW2T, OT0 + 96, h2, h);
    // layer 3: partial dot + quad reduce (DPP)
    float part = 0.0f;
#pragma unroll
    for (int j = 0; j < 8; ++j)
        part = fmaf(R[OT0 + 128 + m8 + j], h[j], part);
    part += dpp_quad<0xB1>(part);
    part += dpp_quad<0x4E>(part);

    const bool act = (k >= 0) && (k < KSUB);
    float wgt = window_w(xg, kc);
    float val = act ? wgt * (part + B3[kc]) : 0.0f;
    if (m == 0) g[pi * 4 + slot] = val;
}

static __device__ __forceinline__ float eval_point(
    float xj, const float* __restrict__ g)
{
    const float scaleT = (float)(TBL - 1);
    float t = fminf(fmaxf(xj * scaleT, 0.0f), scaleT);
    int i0 = (int)t;
    if (i0 > TBL - 2) i0 = TBL - 2;
    float f = t - (float)i0;
    float4 a = *reinterpret_cast<const float4*>(&g[i0 * 4]);
    float4 b = *reinterpret_cast<const float4*>(&g[i0 * 4 + 4]);
    float n0 = (a.x + a.y) + (a.z + a.w);
    float n1 = (b.x + b.y) + (b.z + b.w);
    float num = fmaf(f, n1 - n0, n0);
    float den = den_analytic(xj);
    return num * __builtin_amdgcn_rcpf(den + 1e-12f);
}

__global__ void eval_lerp(const float* __restrict__ x,
                          const float* __restrict__ g,
                          float* __restrict__ out, int N)
{
    int idx = blockIdx.x * blockDim.x + threadIdx.x;
    int base = idx * 4;
    if (base + 3 < N) {
        float4 xv = *reinterpret_cast<const float4*>(&x[base]);
        float4 r;
        r.x = eval_point(xv.x, g);
        r.y = eval_point(xv.y, g);
        r.z = eval_point(xv.z, g);
        r.w = eval_point(xv.w, g);
        *reinterpret_cast<float4*>(&out[base]) = r;
    } else {
        for (int j = base; j < N; ++j) out[j] = eval_point(x[j], g);
    }
}

// ---- fallback path (tiny ws only): direct evaluation via global loads ----
static __device__ __forceinline__ float subnet_eval_g(
    float xn, int kc,
    const float* __restrict__ W0, const float* __restrict__ B0,
    const float* __restrict__ W1, const float* __restrict__ B1,
    const float* __restrict__ W2, const float* __restrict__ B2,
    const float* __restrict__ W3, const float* __restrict__ B3)
{
    float h0[NW], h1[NW];
#pragma unroll
    for (int o = 0; o < NW; ++o)
        h0[o] = fast_tanh(fmaf(W0[kc * NW + o], xn, B0[kc * NW + o]));
#pragma unroll
    for (int o = 0; o < NW; ++o) {
        float a = B1[kc * NW + o];
        const float* row = &W1[kc * NW * NW + o * NW];
#pragma unroll
        for (int j = 0; j < NW; ++j) a = fmaf(row[j], h0[j], a);
        h1[o] = fast_tanh(a);
    }
#pragma unroll
    for (int o = 0; o < NW; ++o) {
        float a = B2[kc * NW + o];
        const float* row = &W2[kc * NW * NW + o * NW];
#pragma unroll
        for (int j = 0; j < NW; ++j) a = fmaf(row[j], h1[j], a);
        h0[o] = fast_tanh(a);
    }
    float a = B3[kc];
#pragma unroll
    for (int j = 0; j < NW; ++j) a = fmaf(W3[kc * NW + j], h0[j], a);
    return a;
}

__global__ void direct_eval(
    const float* __restrict__ x,
    const float* __restrict__ W0, const float* __restrict__ B0,
    const float* __restrict__ W1, const float* __restrict__ B1,
    const float* __restrict__ W2, const float* __restrict__ B2,
    const float* __restrict__ W3, const float* __restrict__ B3,
    float* __restrict__ out, int N)
{
    int n = blockIdx.x * blockDim.x + threadIdx.x;
    if (n >= N) return;
    float xv = x[n];
    float num = 0.f, den = 0.f;
    for (int k = 0; k < KSUB; ++k) {
        float w = window_w(xv, k);
        if (w <= 0.0f) continue;
        float xn = (xv - ((float)k + 0.5f) * 0.0625f) * 10.958904109589041f;
        float o = subnet_eval_g(xn, k, W0, B0, W1, B1, W2, B2, W3, B3);
        num += w * o;
        den += w;
    }
    out[n] = num * __builtin_amdgcn_rcpf(den + 1e-12f);
}

extern "C" void kernel_launch(void* const* d_in, const int* in_sizes, int n_in,
                              void* d_out, int out_size, void* d_ws, size_t ws_size,
                              hipStream_t stream) {
    const float* x  = (const float*)d_in[0];
    const float* W0 = (const float*)d_in[1];
    const float* B0 = (const float*)d_in[2];
    const float* W1 = (const float*)d_in[3];
    const float* B1 = (const float*)d_in[4];
    const float* W2 = (const float*)d_in[5];
    const float* B2 = (const float*)d_in[6];
    const float* W3 = (const float*)d_in[7];
    const float* B3 = (const float*)d_in[8];
    float* out = (float*)d_out;
    const int N = in_sizes[0];

    if ((size_t)TBL * 4 * sizeof(float) <= ws_size) {
        float* g = (float*)d_ws;
        build_tables<<<NSTR * SLOTS, BTHR, 0, stream>>>(
            W0, B0, W1, B1, W2, B2, W3, B3, g);
        int nv = (N + 3) / 4;
        eval_lerp<<<(nv + 255) / 256, 256, 0, stream>>>(x, g, out, N);
    } else {
        direct_eval<<<(N + 255) / 256, 256, 0, stream>>>(
            x, W0, B0, W1, B1, W2, B2, W3, B3, out, N);
    }
}